// Round 17
// baseline (199.394 us; speedup 1.0000x reference)
//
#include <hip/hip_runtime.h>
#include <stdint.h>

// ---------------------------------------------------------------------------
// AttentionBlock: out = hs + (softmax(mask((hs Wq^T+bq)(hs Wk^T+bk)^T /32)) (hs Wv^T+bv)) Wo^T + bo
// B=4, S=2048, D=1024, fp32 in/out. bf16 MFMA compute, fp32 accumulate.
// r16 champion (178.0 us) + ONE change: QKV now uses the verified 8-phase
// 256x256 engine (qkv8), same schedule/vmcnt ledger as scores8. Epilogue:
// tn 0-3 Q (+bias,/32) -> QKb; tn 4-7 K (+bias, mask-zero) -> QKb;
// tn 8-11 V (+bias, mask-zero, full-LDS 256^2 transpose) -> Vt.
// PV and O-proj keep the proven 2-phase engine; scores keeps scores8.
// ---------------------------------------------------------------------------

typedef __attribute__((ext_vector_type(8))) short bf16x8;
typedef __attribute__((ext_vector_type(4))) float f32x4;

typedef __attribute__((address_space(3))) void lds_void_t;
typedef __attribute__((address_space(1))) const void glb_void_t;

__device__ __forceinline__ ushort f2bf(float f) {
  uint32_t u = __float_as_uint(f);
  u += 0x7FFF + ((u >> 16) & 1);   // round-to-nearest-even
  return (ushort)(u >> 16);
}
__device__ __forceinline__ float bf2f(ushort u) {
  return __uint_as_float(((uint32_t)u) << 16);
}

#define BAR   __builtin_amdgcn_s_barrier()
#define SCHED __builtin_amdgcn_sched_barrier(0)
#define LGKM0 asm volatile("s_waitcnt lgkmcnt(0)" ::: "memory")
#define VMC0  asm volatile("s_waitcnt vmcnt(0)" ::: "memory")
#define VMC4  asm volatile("s_waitcnt vmcnt(4)" ::: "memory")

// ---------------------------------------------------------------------------
// Convert fp32 inputs to bf16: X -> Xb, {Wq,Wk,Wv} -> Wqkvb (rows stacked),
// Wo -> Wob. Last block concatenates bq|bk|bv into bqkv (f32).
// ---------------------------------------------------------------------------
__global__ __launch_bounds__(256) void convert_all(
    const float* __restrict__ X, const float* __restrict__ Wq,
    const float* __restrict__ Wk, const float* __restrict__ Wv,
    const float* __restrict__ Wo, const float* __restrict__ bq,
    const float* __restrict__ bk, const float* __restrict__ bv,
    ushort* __restrict__ Xb, ushort* __restrict__ Wqkvb,
    ushort* __restrict__ Wob, float* __restrict__ bqkv) {
  if (blockIdx.x >= 12288) {
#pragma unroll
    for (int u = 0; u < 3; ++u) {
      int base = (u * 256 + threadIdx.x) * 4;
      float4 v = (base < 1024)   ? *(const float4*)(bq + base)
               : (base < 2048)   ? *(const float4*)(bk + base - 1024)
                                 : *(const float4*)(bv + base - 2048);
      *(float4*)(bqkv + base) = v;
    }
    return;
  }
  int64_t o4 = ((int64_t)blockIdx.x * blockDim.x + threadIdx.x) * 4;
  const float* s; ushort* d; int64_t doff, soff;
  if (o4 < 8388608)        { s = X;  d = Xb;    doff = o4;            soff = o4; }
  else if (o4 < 9437184)   { s = Wq; d = Wqkvb; doff = o4 - 8388608;  soff = o4 - 8388608; }
  else if (o4 < 10485760)  { s = Wk; d = Wqkvb; doff = o4 - 8388608;  soff = o4 - 9437184; }
  else if (o4 < 11534336)  { s = Wv; d = Wqkvb; doff = o4 - 8388608;  soff = o4 - 10485760; }
  else                     { s = Wo; d = Wob;   doff = o4 - 11534336; soff = o4 - 11534336; }
  float4 v = *(const float4*)(s + soff);
  ushort4 o;
  o.x = f2bf(v.x); o.y = f2bf(v.y); o.z = f2bf(v.z); o.w = f2bf(v.w);
  *(ushort4*)(d + doff) = o;
}

// ---------------------------------------------------------------------------
// 2-phase GEMM engine (proven): C = A * B^T, BM=128 x BNV, BK=64, 256 thr.
// MODE: 3 = f32 out + bias[col] + resid;  6 = PV normalize.
// GM: group-m supertile factor for XCD-L2 locality.
// ---------------------------------------------------------------------------
#define BM 128
#define BKT 64

template <int MODE, int BNV, int GM>
__global__ __launch_bounds__(256) void gemm_bt(
    const ushort* __restrict__ Ag, const ushort* __restrict__ Bg,
    void* __restrict__ Og, const float* __restrict__ bias,
    const float* __restrict__ resid, ushort* __restrict__ Vt,
    const int* __restrict__ maskg, float* __restrict__ rowsum,
    int M, int N, int K, int lda, int ldb, int ldo,
    long long sAz, long long sBz, long long sOz, float scale) {
  constexpr int NFR = BNV / 32;        // n-frags per wave
  __shared__ ushort LDSu[BM * BKT + BNV * BKT];
  ushort* const As = LDSu;
  ushort* const Bs = LDSu + BM * BKT;
  __shared__ int redn[4];

  const int z = blockIdx.z;
  const ushort* A = Ag + (int64_t)z * sAz;
  const ushort* B = Bg + (int64_t)z * sBz;

  const int tilesN = N / BNV;
  const int q8 = gridDim.x >> 3;
  const int wg = (blockIdx.x & 7) * q8 + (blockIdx.x >> 3);
  const int grpSz = GM * tilesN;
  const int tm = (wg / grpSz) * GM + (wg % GM);
  const int tn = (wg % grpSz) / GM;
  const int tid = threadIdx.x;
  const int wid = tid >> 6;
  const int lane = tid & 63;
  const int lr = lane & 15;
  const int kq = lane >> 4;
  const int wr = (wid >> 1) * 64;
  const int wc = (wid & 1) * (BNV / 2);

  if constexpr (MODE == 6) {
    const int4* mrow = (const int4*)(maskg + z * 2048);
    int4 ma = mrow[tid * 2];
    int4 mb = mrow[tid * 2 + 1];
    int cnt = (ma.x == 0) + (ma.y == 0) + (ma.z == 0) + (ma.w == 0) +
              (mb.x == 0) + (mb.y == 0) + (mb.z == 0) + (mb.w == 0);
#pragma unroll
    for (int off = 1; off < 64; off <<= 1) cnt += __shfl_xor(cnt, off);
    if (lane == 0) redn[wid] = cnt;
  }

  f32x4 acc[4][NFR];
#pragma unroll
  for (int m = 0; m < 4; ++m)
#pragma unroll
    for (int n = 0; n < NFR; ++n) acc[m][n] = (f32x4){0.f, 0.f, 0.f, 0.f};

  const int64_t abase = (int64_t)tm * BM;
  const int64_t bbase = (int64_t)tn * BNV;

  for (int kt = 0; kt < K; kt += BKT) {
    if (kt) __syncthreads();
#pragma unroll
    for (int r = 0; r < 4; ++r) {
      int idx = r * 256 + tid;
      int row = idx >> 3, slot = idx & 7;
      int sslot = slot ^ (row & 7);
      const ushort* ga = A + (abase + row) * lda + kt + sslot * 8;
      ushort* la = &As[(r * 256 + wid * 64) * 8];
      __builtin_amdgcn_global_load_lds((glb_void_t*)ga, (lds_void_t*)la, 16, 0, 0);
    }
#pragma unroll
    for (int r = 0; r < BNV / 32; ++r) {
      int idx = r * 256 + tid;
      int row = idx >> 3, slot = idx & 7;
      int sslot = slot ^ (row & 7);
      const ushort* gb = B + (bbase + row) * ldb + kt + sslot * 8;
      ushort* lb = &Bs[(r * 256 + wid * 64) * 8];
      __builtin_amdgcn_global_load_lds((glb_void_t*)gb, (lds_void_t*)lb, 16, 0, 0);
    }
    __syncthreads();

#pragma unroll
    for (int kk = 0; kk < 2; ++kk) {
      bf16x8 af[4], bfr[NFR];
#pragma unroll
      for (int m = 0; m < 4; ++m) {
        int row = wr + m * 16 + lr;
        int slot = (kk * 4 + kq) ^ (row & 7);
        af[m] = *(const bf16x8*)&As[row * 64 + slot * 8];
      }
#pragma unroll
      for (int n = 0; n < NFR; ++n) {
        int col = wc + n * 16 + lr;
        int slot = (kk * 4 + kq) ^ (col & 7);
        bfr[n] = *(const bf16x8*)&Bs[col * 64 + slot * 8];
      }
#pragma unroll
      for (int m = 0; m < 4; ++m)
#pragma unroll
        for (int n = 0; n < NFR; ++n)
          acc[m][n] = __builtin_amdgcn_mfma_f32_16x16x32_bf16(af[m], bfr[n], acc[m][n], 0, 0, 0);
    }
  }

  if constexpr (MODE == 6) {
    float nm = (float)(redn[0] + redn[1] + redn[2] + redn[3]);
    float invr[4][4];
#pragma unroll
    for (int m = 0; m < 4; ++m)
#pragma unroll
      for (int i = 0; i < 4; ++i)
        invr[m][i] =
            1.0f / (rowsum[z * 2048 + tm * BM + wr + m * 16 + kq * 4 + i] - nm);
#pragma unroll
    for (int m = 0; m < 4; ++m) {
      int r0 = tm * BM + wr + m * 16 + kq * 4;
#pragma unroll
      for (int n = 0; n < NFR; ++n) {
        int c = tn * BNV + wc + n * 16 + lr;
#pragma unroll
        for (int i = 0; i < 4; ++i)
          ((ushort*)Og)[(int64_t)z * sOz + (int64_t)(r0 + i) * ldo + c] =
              f2bf(acc[m][n][i] * invr[m][i]);
      }
    }
  } else {  // MODE 3
#pragma unroll
    for (int m = 0; m < 4; ++m) {
      int r0 = tm * BM + wr + m * 16 + kq * 4;
#pragma unroll
      for (int n = 0; n < NFR; ++n) {
        int c = tn * BNV + wc + n * 16 + lr;
        const float bb = bias[c];
#pragma unroll
        for (int i = 0; i < 4; ++i) {
          int rrow = r0 + i;
          ((float*)Og)[(int64_t)rrow * ldo + c] =
              acc[m][n][i] + bb + resid[(int64_t)rrow * ldo + c];
        }
      }
    }
  }
}

// ---------------------------------------------------------------------------
// 8-phase 256x256 engine core: 512 thr (8 waves 2Mx4N, 128x64 each),
// BK=64, 2 K-tiles/iter, 1 half-tile staged per phase, counted vmcnt(4)
// gates at ph3/ph7, never 0 mid-loop; setprio around 16-MFMA clusters.
// Shared by scores8 (strides 2048) and qkv8 (strides 1024) via LDAB.
// ---------------------------------------------------------------------------
#define SGA(BUF, H, KT) do {                                                   \
    __builtin_amdgcn_global_load_lds(                                          \
        (glb_void_t*)(gA + (int64_t)((H) * 128) * LDAB + (KT)),                \
        (lds_void_t*)(AsU + (((BUF) * 2 + (H)) * 1024 + tid) * 8), 16, 0, 0);  \
    __builtin_amdgcn_global_load_lds(                                          \
        (glb_void_t*)(gA + (int64_t)((H) * 128 + 64) * LDAB + (KT)),           \
        (lds_void_t*)(AsU + (((BUF) * 2 + (H)) * 1024 + 512 + tid) * 8), 16, 0, 0); \
  } while (0)
#define SGB(BUF, H, KT) do {                                                   \
    __builtin_amdgcn_global_load_lds(                                          \
        (glb_void_t*)(gB + (int64_t)((H) * 128) * LDAB + (KT)),                \
        (lds_void_t*)(BsU + (((BUF) * 2 + (H)) * 1024 + tid) * 8), 16, 0, 0);  \
    __builtin_amdgcn_global_load_lds(                                          \
        (glb_void_t*)(gB + (int64_t)((H) * 128 + 64) * LDAB + (KT)),           \
        (lds_void_t*)(BsU + (((BUF) * 2 + (H)) * 1024 + 512 + tid) * 8), 16, 0, 0); \
  } while (0)
#define RDA1(BUF, MH, MQ) {                                                    \
    int rr = ((MH) * 4 + (MQ)) * 16 + lr;                                      \
    const ushort* p_ = AsU + ((BUF) * 2 + wrh) * 8192 + rr * 64;               \
    a[MQ][0] = *(const bf16x8*)(p_ + rsw0);                                    \
    a[MQ][1] = *(const bf16x8*)(p_ + rsw1); }
#define RDA(BUF, MH) RDA1(BUF, MH, 0) RDA1(BUF, MH, 1) RDA1(BUF, MH, 2) RDA1(BUF, MH, 3)
#define RDB1(BUF, NH, NQ) {                                                    \
    int n_ = (NH) * 2 + (NQ);                                                  \
    int cc = wcin + n_ * 16 + lr;                                              \
    const ushort* p_ = BsU + ((BUF) * 2 + hB) * 8192 + cc * 64;                \
    bb[n_][0] = *(const bf16x8*)(p_ + rsw0);                                   \
    bb[n_][1] = *(const bf16x8*)(p_ + rsw1); }
#define RDB(BUF, NH) RDB1(BUF, NH, 0) RDB1(BUF, NH, 1)
#define MM2X(MH, MQ, N) \
    acc[(MH)*4+(MQ)][N] = __builtin_amdgcn_mfma_f32_16x16x32_bf16(a[MQ][0], bb[N][0], acc[(MH)*4+(MQ)][N], 0, 0, 0); \
    acc[(MH)*4+(MQ)][N] = __builtin_amdgcn_mfma_f32_16x16x32_bf16(a[MQ][1], bb[N][1], acc[(MH)*4+(MQ)][N], 0, 0, 0);
#define CL8(MH, NH) \
    __builtin_amdgcn_s_setprio(1); \
    MM2X(MH, 0, (NH)*2) MM2X(MH, 0, (NH)*2+1) MM2X(MH, 1, (NH)*2) MM2X(MH, 1, (NH)*2+1) \
    MM2X(MH, 2, (NH)*2) MM2X(MH, 2, (NH)*2+1) MM2X(MH, 3, (NH)*2) MM2X(MH, 3, (NH)*2+1) \
    __builtin_amdgcn_s_setprio(0);

#define KLOOP8                                                                  \
  SGA(0, 0, 0); SGA(0, 1, 0); SGB(0, 0, 0); SGB(0, 1, 0);                       \
  SGB(1, 0, 64); SGB(1, 1, 64);                                                 \
  VMC4; BAR; SCHED;                                                             \
  for (int it = 0; it < 8; ++it) {                                              \
    const bool last = (it == 7);                                                \
    const int ktA1 = it * 128 + 64;                                             \
    const int ktN = it * 128 + 128;                                             \
    const int ktN1 = it * 128 + 192;                                            \
    RDA(0, 0) RDB(0, 0)                                                         \
    SGA(1, 0, ktA1);                                                            \
    BAR; LGKM0; SCHED;                                                          \
    CL8(0, 0)                                                                   \
    SCHED; BAR;                                                                 \
    RDB(0, 1)                                                                   \
    SGA(1, 1, ktA1);                                                            \
    BAR; LGKM0; SCHED;                                                          \
    CL8(0, 1)                                                                   \
    SCHED; BAR;                                                                 \
    RDA(0, 1)                                                                   \
    if (!last) { SGB(0, 0, ktN); }                                              \
    BAR; LGKM0; SCHED;                                                          \
    CL8(1, 1)                                                                   \
    SCHED; BAR;                                                                 \
    if (!last) { SGB(0, 1, ktN); }                                              \
    CL8(1, 0)                                                                   \
    SCHED;                                                                      \
    if (last) { VMC0; } else { VMC4; }                                          \
    BAR;                                                                        \
    RDA(1, 0) RDB(1, 0)                                                         \
    if (!last) { SGA(0, 0, ktN); }                                              \
    BAR; LGKM0; SCHED;                                                          \
    CL8(0, 0)                                                                   \
    SCHED; BAR;                                                                 \
    RDB(1, 1)                                                                   \
    if (!last) { SGA(0, 1, ktN); }                                              \
    BAR; LGKM0; SCHED;                                                          \
    CL8(0, 1)                                                                   \
    SCHED; BAR;                                                                 \
    RDA(1, 1)                                                                   \
    if (!last) { SGB(1, 0, ktN1); }                                             \
    BAR; LGKM0; SCHED;                                                          \
    CL8(1, 1)                                                                   \
    SCHED; BAR;                                                                 \
    if (!last) { SGB(1, 1, ktN1); }                                             \
    CL8(1, 0)                                                                   \
    SCHED;                                                                      \
    if (!last) { VMC4; BAR; }                                                   \
  }

// ---------------------------------------------------------------------------
// scores8: P' = exp(Q K^T) + rowsum.  Grid (64,1,4) = 256 blocks.
// ---------------------------------------------------------------------------
__global__ __launch_bounds__(512, 2) void scores8(
    const ushort* __restrict__ QKg, ushort* __restrict__ P,
    float* __restrict__ rowsum) {
  __shared__ ushort AsU[32768];
  __shared__ ushort BsU[32768];
  constexpr int LDAB = 2048;

  const int z = blockIdx.z;
  const ushort* Ab = QKg + (int64_t)z * (2048 * 2048);
  const ushort* Bb = Ab + 1024;
  const int64_t zoff = (int64_t)z * (2048 * 2048);

  const int q8 = gridDim.x >> 3;
  const int wg = (blockIdx.x & 7) * q8 + (blockIdx.x >> 3);
  const int tm = wg >> 3, tn = wg & 7;

  const int tid = threadIdx.x;
  const int wid = tid >> 6, lane = tid & 63;
  const int lr = lane & 15, kq = lane >> 4;
  const int wrh = wid >> 2;
  const int wcq = wid & 3;
  const int hB = wcq >> 1;
  const int wcin = (wcq & 1) * 64;

  const int r0 = tid >> 3;
  const int g0 = ((tid & 7) ^ (r0 & 7)) * 8;
  const ushort* gA = Ab + (int64_t)(tm * 256 + r0) * LDAB + g0;
  const ushort* gB = Bb + (int64_t)(tn * 256 + r0) * LDAB + g0;

  const int rsw0 = (kq ^ (lr & 7)) * 8;
  const int rsw1 = rsw0 ^ 32;

  bf16x8 a[4][2], bb[4][2];
  f32x4 acc[8][4];
#pragma unroll
  for (int m = 0; m < 8; ++m)
#pragma unroll
    for (int n = 0; n < 4; ++n) acc[m][n] = (f32x4){0.f, 0.f, 0.f, 0.f};

  KLOOP8

  // epilogue: exp + P store + rowsum
  float part[8][4];
#pragma unroll
  for (int m = 0; m < 8; ++m)
#pragma unroll
    for (int i = 0; i < 4; ++i) part[m][i] = 0.f;
  const int colb = tn * 256 + wcq * 64;
#pragma unroll
  for (int m = 0; m < 8; ++m) {
    const int rl = wrh * 128 + m * 16 + kq * 4;
#pragma unroll
    for (int n = 0; n < 4; ++n) {
      const int c = colb + n * 16 + lr;
#pragma unroll
      for (int i = 0; i < 4; ++i) {
        float e = __expf(acc[m][n][i]);
        P[zoff + (int64_t)(tm * 256 + rl + i) * 2048 + c] = f2bf(e);
        part[m][i] += e;
      }
    }
  }
#pragma unroll
  for (int off = 1; off <= 8; off <<= 1)
#pragma unroll
    for (int m = 0; m < 8; ++m)
#pragma unroll
      for (int i = 0; i < 4; ++i)
        part[m][i] += __shfl_xor(part[m][i], off);
  float* pbuf = (float*)AsU;
  if (lr == 0) {
#pragma unroll
    for (int m = 0; m < 8; ++m)
#pragma unroll
      for (int i = 0; i < 4; ++i)
        pbuf[wcq * 256 + wrh * 128 + m * 16 + kq * 4 + i] = part[m][i];
  }
  __syncthreads();
  if (tid < 256) {
    float s = pbuf[tid] + pbuf[256 + tid] + pbuf[512 + tid] + pbuf[768 + tid];
    atomicAdd(&rowsum[z * 2048 + tm * 256 + tid], s);
  }
}

// ---------------------------------------------------------------------------
// qkv8: [Q/32 | K-masked | V->Vt] = X W^T + b on the 8-phase 256^2 engine.
// Grid 384 blocks (32 tm x 12 tn), XCD chunk 48, GM=4 supertile.
// tn 0-3: Q -> QKb cols 0-1023 (+bias, x1/32)
// tn 4-7: K -> QKb cols 1024-2047 (+bias, masked token rows zeroed)
// tn 8-11: V (+bias, mask-zero) -> full-LDS 256^2 transpose -> Vt[e][token]
// ---------------------------------------------------------------------------
__global__ __launch_bounds__(512, 2) void qkv8(
    const ushort* __restrict__ Xg, const ushort* __restrict__ Wg,
    ushort* __restrict__ QKb, const float* __restrict__ bias,
    ushort* __restrict__ Vt, const int* __restrict__ maskg) {
  __shared__ ushort LDS2[65536];   // 128 KB: As | Bs
  ushort* const AsU = LDS2;
  ushort* const BsU = LDS2 + 32768;
  constexpr int LDAB = 1024;

  const int q8 = gridDim.x >> 3;           // 48
  const int wg = (blockIdx.x & 7) * q8 + (blockIdx.x >> 3);
  const int tm = (wg / 48) * 4 + (wg & 3); // GM=4, grpSz = 4*12 = 48
  const int tn = (wg % 48) >> 2;

  const int tid = threadIdx.x;
  const int wid = tid >> 6, lane = tid & 63;
  const int lr = lane & 15, kq = lane >> 4;
  const int wrh = wid >> 2;
  const int wcq = wid & 3;
  const int hB = wcq >> 1;
  const int wcin = (wcq & 1) * 64;

  const int r0 = tid >> 3;
  const int g0 = ((tid & 7) ^ (r0 & 7)) * 8;
  const ushort* gA = Xg + (int64_t)(tm * 256 + r0) * LDAB + g0;
  const ushort* gB = Wg + (int64_t)(tn * 256 + r0) * LDAB + g0;

  const int rsw0 = (kq ^ (lr & 7)) * 8;
  const int rsw1 = rsw0 ^ 32;

  bf16x8 a[4][2], bb[4][2];
  f32x4 acc[8][4];
#pragma unroll
  for (int m = 0; m < 8; ++m)
#pragma unroll
    for (int n = 0; n < 4; ++n) acc[m][n] = (f32x4){0.f, 0.f, 0.f, 0.f};

  KLOOP8

  // ---- epilogue
  const int clw = wcq * 64;   // wave col base within 256
  if (tn < 8) {
    // Q (scale 1/32) or K (mask-zero rows); direct store to QKb (ld 2048)
    const float qscale = (tn < 4) ? 0.03125f : 1.0f;
    const bool isK = (tn >= 4);
#pragma unroll
    for (int m = 0; m < 8; ++m) {
      const int rg = tm * 256 + wrh * 128 + m * 16 + kq * 4;
      int mk[4] = {1, 1, 1, 1};
      if (isK) {
        int4 mv = *(const int4*)(maskg + rg);
        mk[0] = mv.x; mk[1] = mv.y; mk[2] = mv.z; mk[3] = mv.w;
      }
#pragma unroll
      for (int n = 0; n < 4; ++n) {
        const int c = tn * 256 + clw + n * 16 + lr;
        const float bbv = bias[c];
#pragma unroll
        for (int i = 0; i < 4; ++i) {
          ushort v = mk[i] ? f2bf((acc[m][n][i] + bbv) * qscale) : (ushort)0;
          QKb[(int64_t)(rg + i) * 2048 + c] = v;
        }
      }
    }
  } else {
    // V: bias + mask-zero, 256x256 transpose through the full 128 KB LDS.
    BAR;  // all waves past K-loop (LDS free for reuse)
#pragma unroll
    for (int m = 0; m < 8; ++m) {
      const int rl0 = wrh * 128 + m * 16 + kq * 4;    // local token
      int4 mv = *(const int4*)(maskg + tm * 256 + rl0);
      int mk[4] = {mv.x, mv.y, mv.z, mv.w};
#pragma unroll
      for (int n = 0; n < 4; ++n) {
        const int cl = clw + n * 16 + lr;             // local e
        const float bbv = bias[tn * 256 + cl];
#pragma unroll
        for (int i = 0; i < 4; ++i) {
          const int rl = rl0 + i;
          ushort v = mk[i] ? f2bf(acc[m][n][i] + bbv) : (ushort)0;
          LDS2[cl * 256 + (rl ^ ((cl & 7) << 3))] = v;
        }
      }
    }
    BAR;
    {
      const int e = tid >> 1, h = tid & 1;
      const int sw = (e & 7) << 3;
      ushort* dst = Vt + (int64_t)((tn - 8) * 256 + e) * 8192 + tm * 256 + h * 128;
      const ushort* src = &LDS2[e * 256];
#pragma unroll
      for (int g = 0; g < 16; ++g) {
        const int tb8 = h * 128 + g * 8;
        bf16x8 vv = *(const bf16x8*)&src[tb8 ^ sw];
        *(bf16x8*)&dst[g * 8] = vv;
      }
    }
  }
}

#undef SGA
#undef SGB
#undef RDA1
#undef RDA
#undef RDB1
#undef RDB
#undef MM2X
#undef CL8
#undef KLOOP8

// ---------------------------------------------------------------------------
// Host-side launch
// ---------------------------------------------------------------------------
extern "C" void kernel_launch(void* const* d_in, const int* in_sizes, int n_in,
                              void* d_out, int out_size, void* d_ws, size_t ws_size,
                              hipStream_t stream) {
  const float* hs = (const float*)d_in[0];
  const int* mask = (const int*)d_in[1];
  const float* Wq = (const float*)d_in[2];
  const float* bq = (const float*)d_in[3];
  const float* Wk = (const float*)d_in[4];
  const float* bk = (const float*)d_in[5];
  const float* Wv = (const float*)d_in[6];
  const float* bv = (const float*)d_in[7];
  const float* Wo = (const float*)d_in[8];
  const float* bo = (const float*)d_in[9];
  float* out = (float*)d_out;
  char* w = (char*)d_ws;

  // Workspace layout (bytes), total 120 MiB:
  ushort* Xb    = (ushort*)(w + 0);          // [8192][1024] bf16 (dead after QKV)
  float*  rowsum = (float*)(w + 0);          // 8192 f32 in dead Xb region
  ushort* Wqkvb = (ushort*)(w + 16777216);   // [3072][1024] (Wq;Wk;Wv rows)
  ushort* Wob   = (ushort*)(w + 23068672);   // [1024][1024]
  ushort* QKb   = (ushort*)(w + 25165824);   // [8192][2048] (cols: Q/32 | K-masked)
  ushort* Vt    = (ushort*)(w + 58720256);   // [1024][8192] (V^T, masked cols zeroed)
  ushort* P     = (ushort*)(w + 75497472);   // [4][2048][2048]
  float*  bqkv  = (float*)(w + 92274688);    // 3072 f32 in P region (dead by scores)
  ushort* AO    = (ushort*)(w + 109051904);  // [4][2048][1024]

  // 1. fp32 -> bf16 packing (+ bias concat)
  convert_all<<<12289, 256, 0, stream>>>(hs, Wq, Wk, Wv, Wo, bq, bk, bv,
                                         Xb, Wqkvb, Wob, bqkv);

  // 2. [Q/32 | K-masked | V->Vt] = X [Wq;Wk;Wv]^T + b, 8-phase 256^2 engine
  //    -> 32x12 = 384 blocks
  qkv8<<<dim3(384, 1, 1), 512, 0, stream>>>(Xb, Wqkvb, QKb, bqkv, Vt, mask);

  // 3. zero rowsum (Xb region now dead)
  hipMemsetAsync(rowsum, 0, 8192 * sizeof(float), stream);

  // 4. P' = exp(Q K^T) + rowsum, 8-phase 256^2 engine -> 64x4 = 256 blocks
  scores8<<<dim3(64, 1, 4), 512, 0, stream>>>(QKb, P, rowsum);

  // 5. AO = (P' V) / (rowsum - nmask)  per batch -> 128x4 blocks, GM=4
  gemm_bt<6, 128, 4><<<dim3(128, 1, 4), 256, 0, stream>>>(P, Vt, AO, nullptr,
      nullptr, nullptr, mask, rowsum,
      2048, 1024, 2048, 2048, 8192, 1024,
      (long long)2048 * 2048, (long long)2048, (long long)2048 * 1024, 1.f);

  // 6. out = AO Wo^T + bo + hs (fp32, M=8192, N=1024) -> 1024 blocks, GM=8
  gemm_bt<3, 64, 8><<<dim3(1024, 1, 1), 256, 0, stream>>>(AO, Wob, (void*)out, bo,
      hs, nullptr, nullptr, nullptr,
      8192, 1024, 1024, 1024, 1024, 1024, 0, 0, 0, 1.f);
}

// Round 18
// 177.600 us; speedup vs baseline: 1.1227x; 1.1227x over previous
//
#include <hip/hip_runtime.h>
#include <stdint.h>

// ---------------------------------------------------------------------------
// AttentionBlock: out = hs + (softmax(mask((hs Wq^T+bq)(hs Wk^T+bk)^T /32)) (hs Wv^T+bv)) Wo^T + bo
// B=4, S=2048, D=1024, fp32 in/out. bf16 MFMA compute, fp32 accumulate.
// r16 champion configuration (178.0 us), restored after r17's qkv8 A/B
// (8-phase QKV, 384 blocks @ 1 blk/CU = 2 rounds) measured -21 us worse.
// Pipeline: convert -> QKV (2-phase 128x128, fused Q/32 + K-mask + V->Vt
// transpose) -> memset rowsum -> scores8 (8-phase 256x256, fused exp+rowsum,
// grid exactly 256 = 1.0 rounds) -> PV (2-phase, 1/(rowsum-nmask)) ->
// O-proj (2-phase 128x64 + bias + residual).
// ---------------------------------------------------------------------------

typedef __attribute__((ext_vector_type(8))) short bf16x8;
typedef __attribute__((ext_vector_type(4))) float f32x4;

typedef __attribute__((address_space(3))) void lds_void_t;
typedef __attribute__((address_space(1))) const void glb_void_t;

__device__ __forceinline__ ushort f2bf(float f) {
  uint32_t u = __float_as_uint(f);
  u += 0x7FFF + ((u >> 16) & 1);   // round-to-nearest-even
  return (ushort)(u >> 16);
}
__device__ __forceinline__ float bf2f(ushort u) {
  return __uint_as_float(((uint32_t)u) << 16);
}

#define BAR   __builtin_amdgcn_s_barrier()
#define SCHED __builtin_amdgcn_sched_barrier(0)
#define LGKM0 asm volatile("s_waitcnt lgkmcnt(0)" ::: "memory")
#define VMC0  asm volatile("s_waitcnt vmcnt(0)" ::: "memory")
#define VMC4  asm volatile("s_waitcnt vmcnt(4)" ::: "memory")

// ---------------------------------------------------------------------------
// Convert fp32 inputs to bf16: X -> Xb, {Wq,Wk,Wv} -> Wqkvb (rows stacked),
// Wo -> Wob. Last block concatenates bq|bk|bv into bqkv (f32).
// ---------------------------------------------------------------------------
__global__ __launch_bounds__(256) void convert_all(
    const float* __restrict__ X, const float* __restrict__ Wq,
    const float* __restrict__ Wk, const float* __restrict__ Wv,
    const float* __restrict__ Wo, const float* __restrict__ bq,
    const float* __restrict__ bk, const float* __restrict__ bv,
    ushort* __restrict__ Xb, ushort* __restrict__ Wqkvb,
    ushort* __restrict__ Wob, float* __restrict__ bqkv) {
  if (blockIdx.x >= 12288) {
#pragma unroll
    for (int u = 0; u < 3; ++u) {
      int base = (u * 256 + threadIdx.x) * 4;
      float4 v = (base < 1024)   ? *(const float4*)(bq + base)
               : (base < 2048)   ? *(const float4*)(bk + base - 1024)
                                 : *(const float4*)(bv + base - 2048);
      *(float4*)(bqkv + base) = v;
    }
    return;
  }
  int64_t o4 = ((int64_t)blockIdx.x * blockDim.x + threadIdx.x) * 4;
  const float* s; ushort* d; int64_t doff, soff;
  if (o4 < 8388608)        { s = X;  d = Xb;    doff = o4;            soff = o4; }
  else if (o4 < 9437184)   { s = Wq; d = Wqkvb; doff = o4 - 8388608;  soff = o4 - 8388608; }
  else if (o4 < 10485760)  { s = Wk; d = Wqkvb; doff = o4 - 8388608;  soff = o4 - 9437184; }
  else if (o4 < 11534336)  { s = Wv; d = Wqkvb; doff = o4 - 8388608;  soff = o4 - 10485760; }
  else                     { s = Wo; d = Wob;   doff = o4 - 11534336; soff = o4 - 11534336; }
  float4 v = *(const float4*)(s + soff);
  ushort4 o;
  o.x = f2bf(v.x); o.y = f2bf(v.y); o.z = f2bf(v.z); o.w = f2bf(v.w);
  *(ushort4*)(d + doff) = o;
}

// ---------------------------------------------------------------------------
// 2-phase GEMM engine (proven): C = A * B^T, BM=128 x BNV, BK=64, 256 thr.
// MODE: 3 = f32 out + bias[col] + resid;  4 = QKV split;  6 = PV normalize.
// GM: group-m supertile factor for XCD-L2 locality.
// ---------------------------------------------------------------------------
#define BM 128
#define BKT 64

template <int MODE, int BNV, int GM>
__global__ __launch_bounds__(256) void gemm_bt(
    const ushort* __restrict__ Ag, const ushort* __restrict__ Bg,
    void* __restrict__ Og, const float* __restrict__ bias,
    const float* __restrict__ resid, ushort* __restrict__ Vt,
    const int* __restrict__ maskg, float* __restrict__ rowsum,
    int M, int N, int K, int lda, int ldb, int ldo,
    long long sAz, long long sBz, long long sOz, float scale) {
  constexpr int NFR = BNV / 32;        // n-frags per wave
  __shared__ ushort LDSu[BM * BKT + BNV * BKT];
  ushort* const As = LDSu;
  ushort* const Bs = LDSu + BM * BKT;
  __shared__ int redn[4];

  const int z = blockIdx.z;
  const ushort* A = Ag + (int64_t)z * sAz;
  const ushort* B = Bg + (int64_t)z * sBz;

  const int tilesN = N / BNV;
  const int q8 = gridDim.x >> 3;
  const int wg = (blockIdx.x & 7) * q8 + (blockIdx.x >> 3);
  const int grpSz = GM * tilesN;
  const int tm = (wg / grpSz) * GM + (wg % GM);
  const int tn = (wg % grpSz) / GM;
  const int tid = threadIdx.x;
  const int wid = tid >> 6;
  const int lane = tid & 63;
  const int lr = lane & 15;
  const int kq = lane >> 4;
  const int wr = (wid >> 1) * 64;
  const int wc = (wid & 1) * (BNV / 2);

  if constexpr (MODE == 6) {
    const int4* mrow = (const int4*)(maskg + z * 2048);
    int4 ma = mrow[tid * 2];
    int4 mb = mrow[tid * 2 + 1];
    int cnt = (ma.x == 0) + (ma.y == 0) + (ma.z == 0) + (ma.w == 0) +
              (mb.x == 0) + (mb.y == 0) + (mb.z == 0) + (mb.w == 0);
#pragma unroll
    for (int off = 1; off < 64; off <<= 1) cnt += __shfl_xor(cnt, off);
    if (lane == 0) redn[wid] = cnt;
  }

  f32x4 acc[4][NFR];
#pragma unroll
  for (int m = 0; m < 4; ++m)
#pragma unroll
    for (int n = 0; n < NFR; ++n) acc[m][n] = (f32x4){0.f, 0.f, 0.f, 0.f};

  const int64_t abase = (int64_t)tm * BM;
  const int64_t bbase = (int64_t)tn * BNV;

  for (int kt = 0; kt < K; kt += BKT) {
    if (kt) __syncthreads();
#pragma unroll
    for (int r = 0; r < 4; ++r) {
      int idx = r * 256 + tid;
      int row = idx >> 3, slot = idx & 7;
      int sslot = slot ^ (row & 7);
      const ushort* ga = A + (abase + row) * lda + kt + sslot * 8;
      ushort* la = &As[(r * 256 + wid * 64) * 8];
      __builtin_amdgcn_global_load_lds((glb_void_t*)ga, (lds_void_t*)la, 16, 0, 0);
    }
#pragma unroll
    for (int r = 0; r < BNV / 32; ++r) {
      int idx = r * 256 + tid;
      int row = idx >> 3, slot = idx & 7;
      int sslot = slot ^ (row & 7);
      const ushort* gb = B + (bbase + row) * ldb + kt + sslot * 8;
      ushort* lb = &Bs[(r * 256 + wid * 64) * 8];
      __builtin_amdgcn_global_load_lds((glb_void_t*)gb, (lds_void_t*)lb, 16, 0, 0);
    }
    __syncthreads();

#pragma unroll
    for (int kk = 0; kk < 2; ++kk) {
      bf16x8 af[4], bfr[NFR];
#pragma unroll
      for (int m = 0; m < 4; ++m) {
        int row = wr + m * 16 + lr;
        int slot = (kk * 4 + kq) ^ (row & 7);
        af[m] = *(const bf16x8*)&As[row * 64 + slot * 8];
      }
#pragma unroll
      for (int n = 0; n < NFR; ++n) {
        int col = wc + n * 16 + lr;
        int slot = (kk * 4 + kq) ^ (col & 7);
        bfr[n] = *(const bf16x8*)&Bs[col * 64 + slot * 8];
      }
#pragma unroll
      for (int m = 0; m < 4; ++m)
#pragma unroll
        for (int n = 0; n < NFR; ++n)
          acc[m][n] = __builtin_amdgcn_mfma_f32_16x16x32_bf16(af[m], bfr[n], acc[m][n], 0, 0, 0);
    }
  }

  if constexpr (MODE == 6) {
    float nm = (float)(redn[0] + redn[1] + redn[2] + redn[3]);
    float invr[4][4];
#pragma unroll
    for (int m = 0; m < 4; ++m)
#pragma unroll
      for (int i = 0; i < 4; ++i)
        invr[m][i] =
            1.0f / (rowsum[z * 2048 + tm * BM + wr + m * 16 + kq * 4 + i] - nm);
#pragma unroll
    for (int m = 0; m < 4; ++m) {
      int r0 = tm * BM + wr + m * 16 + kq * 4;
#pragma unroll
      for (int n = 0; n < NFR; ++n) {
        int c = tn * BNV + wc + n * 16 + lr;
#pragma unroll
        for (int i = 0; i < 4; ++i)
          ((ushort*)Og)[(int64_t)z * sOz + (int64_t)(r0 + i) * ldo + c] =
              f2bf(acc[m][n][i] * invr[m][i]);
      }
    }
  } else if constexpr (MODE == 4) {
    if (tn < 8) {
#pragma unroll
      for (int m = 0; m < 4; ++m) {
        int r0 = tm * BM + wr + m * 16 + kq * 4;
#pragma unroll
        for (int n = 0; n < NFR; ++n) {
          int c = tn * BNV + wc + n * 16 + lr;
          const float bb = bias[c];
#pragma unroll
          for (int i = 0; i < 4; ++i)
            ((ushort*)Og)[(int64_t)(r0 + i) * 2048 + c] =
                f2bf((acc[m][n][i] + bb) * 0.03125f);
        }
      }
    } else if (tn < 16) {
#pragma unroll
      for (int m = 0; m < 4; ++m) {
        int r0 = tm * BM + wr + m * 16 + kq * 4;
        int4 mv = *(const int4*)(maskg + r0);
        int mk[4] = {mv.x, mv.y, mv.z, mv.w};
#pragma unroll
        for (int n = 0; n < NFR; ++n) {
          int c = tn * BNV + wc + n * 16 + lr;
          const float bb = bias[c];
#pragma unroll
          for (int i = 0; i < 4; ++i)
            ((ushort*)Og)[(int64_t)(r0 + i) * 2048 + c] =
                mk[i] ? f2bf(acc[m][n][i] + bb) : (ushort)0;
        }
      }
    } else {
      __syncthreads();
#pragma unroll
      for (int m = 0; m < 4; ++m) {
        int rl0 = wr + m * 16 + kq * 4;
        int4 mv = *(const int4*)(maskg + tm * BM + rl0);
        int mk[4] = {mv.x, mv.y, mv.z, mv.w};
#pragma unroll
        for (int n = 0; n < NFR; ++n) {
          int cl = wc + n * 16 + lr;
          const float bb = bias[tn * BNV + cl];
#pragma unroll
          for (int i = 0; i < 4; ++i) {
            int rl = rl0 + i;
            ushort v = mk[i] ? f2bf(acc[m][n][i] + bb) : (ushort)0;
            LDSu[cl * 128 + (rl ^ ((cl & 7) << 3))] = v;
          }
        }
      }
      __syncthreads();
      {
        const int e = tid >> 1, h = tid & 1;
        ushort* dst = Vt + (int64_t)((tn - 16) * BNV + e) * 8192 + tm * BM + h * 64;
        const ushort* src = &LDSu[e * 128 + h * 64];
#pragma unroll
        for (int g = 0; g < 8; ++g) {
          bf16x8 vv = *(const bf16x8*)&src[((g ^ (e & 7)) & 7) * 8];
          *(bf16x8*)&dst[g * 8] = vv;
        }
      }
    }
  } else {  // MODE 3
#pragma unroll
    for (int m = 0; m < 4; ++m) {
      int r0 = tm * BM + wr + m * 16 + kq * 4;
#pragma unroll
      for (int n = 0; n < NFR; ++n) {
        int c = tn * BNV + wc + n * 16 + lr;
        const float bb = bias[c];
#pragma unroll
        for (int i = 0; i < 4; ++i) {
          int rrow = r0 + i;
          ((float*)Og)[(int64_t)rrow * ldo + c] =
              acc[m][n][i] + bb + resid[(int64_t)rrow * ldo + c];
        }
      }
    }
  }
}

// ---------------------------------------------------------------------------
// scores8: P' = exp(Q K^T) + rowsum, 256x256 tile, BK=64, 512 thr (8 waves
// 2Mx4N, 128x64 each), 8-phase / 2-K-tile schedule, 1 half-tile staged per
// phase, counted vmcnt(4) gates at ph3/ph7 only. Grid (64,1,4) = 256 blocks.
// A = Q (QKb cols 0-1023, pre-scaled 1/32), B = K (cols 1024+), both ld 2048.
// ---------------------------------------------------------------------------
__global__ __launch_bounds__(512, 2) void scores8(
    const ushort* __restrict__ QKg, ushort* __restrict__ P,
    float* __restrict__ rowsum) {
  __shared__ ushort AsU[32768];   // [buf][half][128*64] bf16 = 64 KB
  __shared__ ushort BsU[32768];

  const int z = blockIdx.z;
  const ushort* Ab = QKg + (int64_t)z * (2048 * 2048);
  const ushort* Bb = Ab + 1024;
  const int64_t zoff = (int64_t)z * (2048 * 2048);

  const int q8 = gridDim.x >> 3;
  const int wg = (blockIdx.x & 7) * q8 + (blockIdx.x >> 3);
  const int tm = wg >> 3, tn = wg & 7;

  const int tid = threadIdx.x;
  const int wid = tid >> 6, lane = tid & 63;
  const int lr = lane & 15, kq = lane >> 4;
  const int wrh = wid >> 2;          // A row-half (0/1)
  const int wcq = wid & 3;           // col quarter (0..3)
  const int hB = wcq >> 1;           // B storage half
  const int wcin = (wcq & 1) * 64;   // col offset within B half

  // staging constants: chunk c = slot*512+tid -> row c>>3, granule (c&7)^(r&7)
  const int r0 = tid >> 3;
  const int g0 = ((tid & 7) ^ (r0 & 7)) * 8;
  const ushort* gA = Ab + (int64_t)(tm * 256 + r0) * 2048 + g0;
  const ushort* gB = Bb + (int64_t)(tn * 256 + r0) * 2048 + g0;

#define SGA(BUF, H, KT) do {                                                   \
    __builtin_amdgcn_global_load_lds(                                          \
        (glb_void_t*)(gA + (int64_t)((H) * 128) * 2048 + (KT)),                \
        (lds_void_t*)(AsU + (((BUF) * 2 + (H)) * 1024 + tid) * 8), 16, 0, 0);  \
    __builtin_amdgcn_global_load_lds(                                          \
        (glb_void_t*)(gA + (int64_t)((H) * 128 + 64) * 2048 + (KT)),           \
        (lds_void_t*)(AsU + (((BUF) * 2 + (H)) * 1024 + 512 + tid) * 8), 16, 0, 0); \
  } while (0)
#define SGB(BUF, H, KT) do {                                                   \
    __builtin_amdgcn_global_load_lds(                                          \
        (glb_void_t*)(gB + (int64_t)((H) * 128) * 2048 + (KT)),                \
        (lds_void_t*)(BsU + (((BUF) * 2 + (H)) * 1024 + tid) * 8), 16, 0, 0);  \
    __builtin_amdgcn_global_load_lds(                                          \
        (glb_void_t*)(gB + (int64_t)((H) * 128 + 64) * 2048 + (KT)),           \
        (lds_void_t*)(BsU + (((BUF) * 2 + (H)) * 1024 + 512 + tid) * 8), 16, 0, 0); \
  } while (0)

  const int rsw0 = (kq ^ (lr & 7)) * 8;   // ks0 granule
  const int rsw1 = rsw0 ^ 32;             // ks1 granule (+4)

  bf16x8 a[4][2], bb[4][2];
  f32x4 acc[8][4];
#pragma unroll
  for (int m = 0; m < 8; ++m)
#pragma unroll
    for (int n = 0; n < 4; ++n) acc[m][n] = (f32x4){0.f, 0.f, 0.f, 0.f};

#define RDA1(BUF, MH, MQ) {                                                    \
    int rr = ((MH) * 4 + (MQ)) * 16 + lr;                                      \
    const ushort* p_ = AsU + ((BUF) * 2 + wrh) * 8192 + rr * 64;               \
    a[MQ][0] = *(const bf16x8*)(p_ + rsw0);                                    \
    a[MQ][1] = *(const bf16x8*)(p_ + rsw1); }
#define RDA(BUF, MH) RDA1(BUF, MH, 0) RDA1(BUF, MH, 1) RDA1(BUF, MH, 2) RDA1(BUF, MH, 3)
#define RDB1(BUF, NH, NQ) {                                                    \
    int n_ = (NH) * 2 + (NQ);                                                  \
    int cc = wcin + n_ * 16 + lr;                                              \
    const ushort* p_ = BsU + ((BUF) * 2 + hB) * 8192 + cc * 64;                \
    bb[n_][0] = *(const bf16x8*)(p_ + rsw0);                                   \
    bb[n_][1] = *(const bf16x8*)(p_ + rsw1); }
#define RDB(BUF, NH) RDB1(BUF, NH, 0) RDB1(BUF, NH, 1)
#define MM2X(MH, MQ, N) \
    acc[(MH)*4+(MQ)][N] = __builtin_amdgcn_mfma_f32_16x16x32_bf16(a[MQ][0], bb[N][0], acc[(MH)*4+(MQ)][N], 0, 0, 0); \
    acc[(MH)*4+(MQ)][N] = __builtin_amdgcn_mfma_f32_16x16x32_bf16(a[MQ][1], bb[N][1], acc[(MH)*4+(MQ)][N], 0, 0, 0);
#define CL8(MH, NH) \
    __builtin_amdgcn_s_setprio(1); \
    MM2X(MH, 0, (NH)*2) MM2X(MH, 0, (NH)*2+1) MM2X(MH, 1, (NH)*2) MM2X(MH, 1, (NH)*2+1) \
    MM2X(MH, 2, (NH)*2) MM2X(MH, 2, (NH)*2+1) MM2X(MH, 3, (NH)*2) MM2X(MH, 3, (NH)*2+1) \
    __builtin_amdgcn_s_setprio(0);

  // ---- prologue: T0 complete (8 loads) + T1.B (4 loads); gate leaves T1.B.
  SGA(0, 0, 0); SGA(0, 1, 0); SGB(0, 0, 0); SGB(0, 1, 0);
  SGB(1, 0, 64); SGB(1, 1, 64);
  VMC4; BAR; SCHED;

  for (int it = 0; it < 8; ++it) {
    const bool last = (it == 7);
    const int ktA1 = it * 128 + 64;    // T(2i+1)
    const int ktN = it * 128 + 128;    // T(2i+2)
    const int ktN1 = it * 128 + 192;   // T(2i+3)
    // ph0 (buf0, q(mh0,nh0)): 12 reads; stage T(2i+1).Ah0 -> buf1
    RDA(0, 0) RDB(0, 0)
    SGA(1, 0, ktA1);
    BAR; LGKM0; SCHED;
    CL8(0, 0)
    SCHED; BAR;
    // ph1 (q(mh0,nh1)): 4 reads; stage T(2i+1).Ah1 -> buf1
    RDB(0, 1)
    SGA(1, 1, ktA1);
    BAR; LGKM0; SCHED;
    CL8(0, 1)
    SCHED; BAR;
    // ph2 (q(mh1,nh1)): 8 reads; stage T(2i+2).Bh0 -> buf0 (B free after ph1)
    RDA(0, 1)
    if (!last) { SGB(0, 0, ktN); }
    BAR; LGKM0; SCHED;
    CL8(1, 1)
    SCHED; BAR;
    // ph3 (q(mh1,nh0)): 0 reads; stage T(2i+2).Bh1 -> buf0; GATE buf1 complete
    if (!last) { SGB(0, 1, ktN); }
    CL8(1, 0)
    SCHED;
    if (last) { VMC0; } else { VMC4; }
    BAR;
    // ph4 (buf1, q(mh0,nh0)): stage T(2i+2).Ah0 -> buf0 (A free after ph2)
    RDA(1, 0) RDB(1, 0)
    if (!last) { SGA(0, 0, ktN); }
    BAR; LGKM0; SCHED;
    CL8(0, 0)
    SCHED; BAR;
    // ph5 (q(mh0,nh1)): stage T(2i+2).Ah1 -> buf0
    RDB(1, 1)
    if (!last) { SGA(0, 1, ktN); }
    BAR; LGKM0; SCHED;
    CL8(0, 1)
    SCHED; BAR;
    // ph6 (q(mh1,nh1)): stage T(2i+3).Bh0 -> buf1 (B free after ph5)
    RDA(1, 1)
    if (!last) { SGB(1, 0, ktN1); }
    BAR; LGKM0; SCHED;
    CL8(1, 1)
    SCHED; BAR;
    // ph7 (q(mh1,nh0)): stage T(2i+3).Bh1 -> buf1; GATE next buf0 complete
    if (!last) { SGB(1, 1, ktN1); }
    CL8(1, 0)
    SCHED;
    if (!last) { VMC4; BAR; }
  }

  // ---- epilogue: exp + P store + rowsum (lr-shfl -> LDS combine -> atomics)
  float part[8][4];
#pragma unroll
  for (int m = 0; m < 8; ++m)
#pragma unroll
    for (int i = 0; i < 4; ++i) part[m][i] = 0.f;
  const int colb = tn * 256 + wcq * 64;
#pragma unroll
  for (int m = 0; m < 8; ++m) {
    const int rl = wrh * 128 + m * 16 + kq * 4;   // local row base (0..255)
#pragma unroll
    for (int n = 0; n < 4; ++n) {
      const int c = colb + n * 16 + lr;
#pragma unroll
      for (int i = 0; i < 4; ++i) {
        float e = __expf(acc[m][n][i]);
        P[zoff + (int64_t)(tm * 256 + rl + i) * 2048 + c] = f2bf(e);
        part[m][i] += e;
      }
    }
  }
#pragma unroll
  for (int off = 1; off <= 8; off <<= 1)
#pragma unroll
    for (int m = 0; m < 8; ++m)
#pragma unroll
      for (int i = 0; i < 4; ++i)
        part[m][i] += __shfl_xor(part[m][i], off);
  float* pbuf = (float*)AsU;   // [4][256] f32; loop LDS traffic fully drained
  if (lr == 0) {
#pragma unroll
    for (int m = 0; m < 8; ++m)
#pragma unroll
      for (int i = 0; i < 4; ++i)
        pbuf[wcq * 256 + wrh * 128 + m * 16 + kq * 4 + i] = part[m][i];
  }
  __syncthreads();
  if (tid < 256) {
    float s = pbuf[tid] + pbuf[256 + tid] + pbuf[512 + tid] + pbuf[768 + tid];
    atomicAdd(&rowsum[z * 2048 + tm * 256 + tid], s);
  }
#undef SGA
#undef SGB
#undef RDA1
#undef RDA
#undef RDB1
#undef RDB
#undef MM2X
#undef CL8
}

// ---------------------------------------------------------------------------
// Host-side launch
// ---------------------------------------------------------------------------
extern "C" void kernel_launch(void* const* d_in, const int* in_sizes, int n_in,
                              void* d_out, int out_size, void* d_ws, size_t ws_size,
                              hipStream_t stream) {
  const float* hs = (const float*)d_in[0];
  const int* mask = (const int*)d_in[1];
  const float* Wq = (const float*)d_in[2];
  const float* bq = (const float*)d_in[3];
  const float* Wk = (const float*)d_in[4];
  const float* bk = (const float*)d_in[5];
  const float* Wv = (const float*)d_in[6];
  const float* bv = (const float*)d_in[7];
  const float* Wo = (const float*)d_in[8];
  const float* bo = (const float*)d_in[9];
  float* out = (float*)d_out;
  char* w = (char*)d_ws;

  // Workspace layout (bytes), total 120 MiB:
  ushort* Xb    = (ushort*)(w + 0);          // [8192][1024] bf16 (dead after QKV)
  float*  rowsum = (float*)(w + 0);          // 8192 f32 in dead Xb region
  ushort* Wqkvb = (ushort*)(w + 16777216);   // [3072][1024] (Wq;Wk;Wv rows)
  ushort* Wob   = (ushort*)(w + 23068672);   // [1024][1024]
  ushort* QKb   = (ushort*)(w + 25165824);   // [8192][2048] (cols: Q/32 | K-masked)
  ushort* Vt    = (ushort*)(w + 58720256);   // [1024][8192] (V^T, masked cols zeroed)
  ushort* P     = (ushort*)(w + 75497472);   // [4][2048][2048]
  float*  bqkv  = (float*)(w + 92274688);    // 3072 f32 in P region (dead by scores)
  ushort* AO    = (ushort*)(w + 109051904);  // [4][2048][1024]

  // 1. fp32 -> bf16 packing (+ bias concat)
  convert_all<<<12289, 256, 0, stream>>>(hs, Wq, Wk, Wv, Wo, bq, bk, bv,
                                         Xb, Wqkvb, Wob, bqkv);

  // 2. [Q/32 | K-masked | V->Vt] = X [Wq;Wk;Wv]^T + b  -> 1536 blocks, GM=8
  gemm_bt<4, 128, 8><<<dim3(1536, 1, 1), 256, 0, stream>>>(Xb, Wqkvb, QKb, bqkv,
      nullptr, Vt, mask, nullptr,
      8192, 3072, 1024, 1024, 1024, 2048, 0, 0, 0, 1.f);

  // 3. zero rowsum (Xb region now dead)
  hipMemsetAsync(rowsum, 0, 8192 * sizeof(float), stream);

  // 4. P' = exp(Q K^T) + rowsum, 8-phase 256^2 engine -> 64x4 = 256 blocks
  scores8<<<dim3(64, 1, 4), 512, 0, stream>>>(QKb, P, rowsum);

  // 5. AO = (P' V) / (rowsum - nmask)  per batch -> 128x4 blocks, GM=4
  gemm_bt<6, 128, 4><<<dim3(128, 1, 4), 256, 0, stream>>>(P, Vt, AO, nullptr,
      nullptr, nullptr, mask, rowsum,
      2048, 1024, 2048, 2048, 8192, 1024,
      (long long)2048 * 2048, (long long)2048, (long long)2048 * 1024, 1.f);

  // 6. out = AO Wo^T + bo + hs (fp32, M=8192, N=1024) -> 1024 blocks, GM=8
  gemm_bt<3, 64, 8><<<dim3(1024, 1, 1), 256, 0, stream>>>(AO, Wob, (void*)out, bo,
      hs, nullptr, nullptr, nullptr,
      8192, 1024, 1024, 1024, 1024, 1024, 0, 0, 0, 1.f);
}